// Round 1
// baseline (17145.760 us; speedup 1.0000x reference)
//
#include <hip/hip_runtime.h>
#include <hip/hip_bf16.h>
#include <math.h>

#define NN 10000
#define NE 160000
#define NG 20
#define NZ 10
#define NK 64
#define INV_AVG 0.0625f

__device__ __forceinline__ float silu(float x) {
    return x / (1.0f + expf(-x));
}

// ---------------------------------------------------------------------------
// Kernel 1: feats = node_attrs @ W_embed ; out[batch[n]] += node_attrs @ ae
// ---------------------------------------------------------------------------
__global__ __launch_bounds__(256) void node_init(
    const float* __restrict__ attrs, const float* __restrict__ W_embed,
    const float* __restrict__ ae, const int* __restrict__ batch,
    float* __restrict__ feats, float* __restrict__ out)
{
    int gid = blockIdx.x * blockDim.x + threadIdx.x;
    if (gid >= NN * NK) return;
    int n = gid >> 6, k = gid & 63;
    float acc = 0.f;
#pragma unroll
    for (int z = 0; z < NZ; ++z) acc += attrs[n * NZ + z] * W_embed[z * NK + k];
    feats[gid] = acc;
    if (k == 0) {
        float e0 = 0.f;
#pragma unroll
        for (int z = 0; z < NZ; ++z) e0 += attrs[n * NZ + z] * ae[z];
        atomicAdd(out + batch[n], e0);
    }
}

// ---------------------------------------------------------------------------
// Kernel 2: per-edge radial MLP + spherical harmonics + message scatter
// One wave (64 lanes) per edge; 4 edges per 256-thread block.
// W0/W1/W2 staged in LDS once per block; W3 staged in 16KB chunks.
// ---------------------------------------------------------------------------
__global__ __launch_bounds__(256) void edge_kernel(
    const int* __restrict__ ei, const float* __restrict__ pos,
    const float* __restrict__ feats,
    const float* __restrict__ W0, const float* __restrict__ W1,
    const float* __restrict__ W2, const float* __restrict__ W3,
    float* __restrict__ A, int nquad)
{
    __shared__ float sW0[512];
    __shared__ float sW1[4096];
    __shared__ float sW2[4096];
    __shared__ float sW3[4096];
    __shared__ float sH[4][64];

    const int tid = threadIdx.x;
    const int w = tid >> 6;
    const int lane = tid & 63;

    for (int x = tid; x < 512; x += 256) sW0[x] = W0[x];
    for (int x = tid; x < 4096; x += 256) { sW1[x] = W1[x]; sW2[x] = W2[x]; }
    __syncthreads();

    for (int quad = blockIdx.x; quad < nquad; quad += gridDim.x) {
        const int e = quad * 4 + w;
        const bool ok = (e < NE);
        const int ec = ok ? e : 0;
        const int snd = ei[ec];
        const int rcv = ei[NE + ec];

        const float dx = pos[rcv * 3 + 0] - pos[snd * 3 + 0];
        const float dy = pos[rcv * 3 + 1] - pos[snd * 3 + 1];
        const float dz = pos[rcv * 3 + 2] - pos[snd * 3 + 2];
        const float r2 = dx * dx + dy * dy + dz * dz + 1e-12f;
        const float r = sqrtf(r2);
        const float ir = 1.0f / r;
        const float x = dx * ir, y = dy * ir, z = dz * ir;
        const float xx = x * x, yy = y * y, zz = z * z;

        float Y[16];
        Y[0] = 1.0f;
        Y[1] = 1.73205081f * x;
        Y[2] = 1.73205081f * y;
        Y[3] = 1.73205081f * z;
        Y[4] = 3.87298335f * x * y;
        Y[5] = 3.87298335f * y * z;
        Y[6] = 1.11803399f * (3.0f * zz - 1.0f);
        Y[7] = 3.87298335f * x * z;
        Y[8] = 1.93649167f * (xx - yy);
        Y[9] = 2.09165007f * y * (3.0f * xx - yy);
        Y[10] = 10.2469508f * x * y * z;
        Y[11] = 1.62018517f * y * (5.0f * zz - 1.0f);
        Y[12] = 1.32287566f * z * (5.0f * zz - 3.0f);
        Y[13] = 1.62018517f * x * (5.0f * zz - 1.0f);
        Y[14] = 5.12347538f * z * (xx - yy);
        Y[15] = 2.09165007f * x * (xx - 3.0f * yy);

        const float u = r * 0.2f; // r / R_MAX
        float env = 0.0f;
        if (u < 1.0f) {
            const float u2 = u * u, u4 = u2 * u2, u5 = u4 * u;
            env = 1.0f - 21.0f * u5 + 35.0f * u5 * u - 15.0f * u5 * u2;
        }
        const float cb = 0.632455532f * ir * env; // sqrt(2/R_MAX)/r * env
        const float pu = 3.14159265358979f * u;
        float eb[8];
#pragma unroll
        for (int i = 0; i < 8; ++i) eb[i] = cb * sinf((float)(i + 1) * pu);

        // layer 1: 8 -> 64
        float acc = 0.f;
#pragma unroll
        for (int i = 0; i < 8; ++i) acc += eb[i] * sW0[i * 64 + lane];
        sH[w][lane] = silu(acc);

        // layer 2: 64 -> 64
        acc = 0.f;
#pragma unroll 8
        for (int i = 0; i < 64; ++i) acc += sH[w][i] * sW1[i * 64 + lane];
        float h2 = silu(acc);
        sH[w][lane] = h2;

        // layer 3: 64 -> 64
        acc = 0.f;
#pragma unroll 8
        for (int i = 0; i < 64; ++i) acc += sH[w][i] * sW2[i * 64 + lane];
        float h3 = silu(acc);
        sH[w][lane] = h3;

        float f = 0.f;
        if (ok) f = feats[snd * 64 + lane] * INV_AVG;

        // layer 4: 64 -> 256 (no activation). lane k holds R[k][0..3].
        float a0 = 0.f, a1 = 0.f, a2 = 0.f, a3 = 0.f;
#pragma unroll
        for (int c = 0; c < 4; ++c) {
            __syncthreads();
            for (int xq = tid; xq < 4096; xq += 256) sW3[xq] = W3[c * 4096 + xq];
            __syncthreads();
#pragma unroll
            for (int i = 0; i < 16; ++i) {
                const float hh = sH[w][c * 16 + i];
                const float4 wv = ((const float4*)sW3)[i * 64 + lane];
                a0 += hh * wv.x; a1 += hh * wv.y; a2 += hh * wv.z; a3 += hh * wv.w;
            }
        }

        if (ok) {
            float* Ap = A + ((size_t)rcv * 64 + lane) * 16;
            const float f0 = f * a0, f1 = f * a1, f2 = f * a2, f3 = f * a3;
            atomicAdd(Ap + 0,  f0 * Y[0]);
            atomicAdd(Ap + 1,  f1 * Y[1]);
            atomicAdd(Ap + 2,  f1 * Y[2]);
            atomicAdd(Ap + 3,  f1 * Y[3]);
            atomicAdd(Ap + 4,  f2 * Y[4]);
            atomicAdd(Ap + 5,  f2 * Y[5]);
            atomicAdd(Ap + 6,  f2 * Y[6]);
            atomicAdd(Ap + 7,  f2 * Y[7]);
            atomicAdd(Ap + 8,  f2 * Y[8]);
            atomicAdd(Ap + 9,  f3 * Y[9]);
            atomicAdd(Ap + 10, f3 * Y[10]);
            atomicAdd(Ap + 11, f3 * Y[11]);
            atomicAdd(Ap + 12, f3 * Y[12]);
            atomicAdd(Ap + 13, f3 * Y[13]);
            atomicAdd(Ap + 14, f3 * Y[14]);
            atomicAdd(Ap + 15, f3 * Y[15]);
        }
    }
}

// ---------------------------------------------------------------------------
// Kernel 3: per-node mix (einsum) + gate + W_out + energy readout
// One block (256 threads) per node.
// ---------------------------------------------------------------------------
__global__ __launch_bounds__(256) void node_update(
    const float* __restrict__ A, const float* __restrict__ attrs,
    const float* __restrict__ Wmix, const float* __restrict__ Wz,
    const float* __restrict__ Wout, const float* __restrict__ wread1,
    const float* __restrict__ Wr1, const float* __restrict__ wr2,
    const int* __restrict__ batch,
    float* __restrict__ feats, float* __restrict__ out, int t)
{
    __shared__ float sA[1024];    // [k][m]
    __shared__ float sNew[1024];  // [m][c]
    __shared__ float sB[64];
    __shared__ float sF[64];

    const int n = blockIdx.x;
    const int tid = threadIdx.x;

    for (int xq = tid; xq < 1024; xq += 256) sA[xq] = A[(size_t)n * 1024 + xq];
    __syncthreads();

    const int c = tid & 63;
    const int mg = tid >> 6;

    // l(m) lookup, computed (uniform per thread)
    int lsq[4];
#pragma unroll
    for (int q = 0; q < 4; ++q) {
        const int m = mg * 4 + q;
        lsq[q] = (m == 0) ? 0 : (m < 4) ? 1 : (m < 9) ? 2 : 3;
    }

    float accq[4] = {0.f, 0.f, 0.f, 0.f};
    for (int k = 0; k < 64; ++k) {
#pragma unroll
        for (int q = 0; q < 4; ++q) {
            const int m = mg * 4 + q;
            accq[q] += sA[k * 16 + m] * Wmix[lsq[q] * 4096 + k * 64 + c];
        }
    }
#pragma unroll
    for (int q = 0; q < 4; ++q) sNew[(mg * 4 + q) * 64 + c] = accq[q];
    __syncthreads();

    if (tid < 64) {
        const float s1 = sNew[c];
        float inv2 = 0.f;
#pragma unroll
        for (int m = 0; m < 16; ++m) {
            const float v = sNew[m * 64 + c];
            inv2 += v * v;
        }
        float z0 = 0.f, z1 = 0.f, z2 = 0.f;
#pragma unroll
        for (int zz = 0; zz < NZ; ++zz) {
            const float a = attrs[n * NZ + zz];
            z0 += a * Wz[(t * 3 + 0) * 640 + zz * 64 + c];
            z1 += a * Wz[(t * 3 + 1) * 640 + zz * 64 + c];
            z2 += a * Wz[(t * 3 + 2) * 640 + zz * 64 + c];
        }
        sB[c] = z0 * s1 + z1 * inv2 + z2 * (s1 * inv2);
    }
    __syncthreads();

    if (tid < 64) {
        float acc = 0.f;
#pragma unroll 8
        for (int j = 0; j < 64; ++j) acc += sB[j] * Wout[j * 64 + c];
        feats[(size_t)n * 64 + c] = acc;
        sF[c] = acc;
    }
    __syncthreads();

    if (t == 0) {
        if (tid < 64) {
            float v = sF[tid] * wread1[tid];
#pragma unroll
            for (int off = 32; off > 0; off >>= 1) v += __shfl_down(v, off, 64);
            if (tid == 0) atomicAdd(out + batch[n], v);
        }
    } else {
        if (tid < 16) {
            float acc = 0.f;
#pragma unroll
            for (int j = 0; j < 64; ++j) acc += sF[j] * Wr1[j * 16 + tid];
            float v = silu(acc) * wr2[tid];
#pragma unroll
            for (int off = 8; off > 0; off >>= 1) v += __shfl_down(v, off, 64);
            if (tid == 0) atomicAdd(out + batch[n], v);
        }
    }
}

// ---------------------------------------------------------------------------
extern "C" void kernel_launch(void* const* d_in, const int* in_sizes, int n_in,
                              void* d_out, int out_size, void* d_ws, size_t ws_size,
                              hipStream_t stream) {
    const float* attrs   = (const float*)d_in[0];
    const float* pos     = (const float*)d_in[1];
    const int*   ei      = (const int*)d_in[2];
    const int*   batch   = (const int*)d_in[3];
    const float* ae      = (const float*)d_in[4];
    const float* W_embed = (const float*)d_in[5];
    const float* rW0     = (const float*)d_in[6];
    const float* rW1     = (const float*)d_in[7];
    const float* rW2     = (const float*)d_in[8];
    const float* rW3     = (const float*)d_in[9];
    const float* Wmix    = (const float*)d_in[10];
    const float* Wz      = (const float*)d_in[11];
    const float* Wout    = (const float*)d_in[12];
    const float* wread1  = (const float*)d_in[13];
    const float* Wr1     = (const float*)d_in[14];
    const float* wr2     = (const float*)d_in[15];
    float* out = (float*)d_out;

    float* A     = (float*)d_ws;                          // NN*64*16 f32 = 40.96 MB
    float* feats = (float*)((char*)d_ws + (size_t)NN * 1024 * 4); // NN*64 f32

    hipMemsetAsync(out, 0, out_size * sizeof(float), stream);

    node_init<<<(NN * NK + 255) / 256, 256, 0, stream>>>(attrs, W_embed, ae, batch, feats, out);

    const int nquad = (NE + 3) / 4;
    for (int t = 0; t < 2; ++t) {
        hipMemsetAsync(A, 0, (size_t)NN * 1024 * sizeof(float), stream);
        edge_kernel<<<2560, 256, 0, stream>>>(
            ei, pos, feats,
            rW0 + t * 512, rW1 + t * 4096, rW2 + t * 4096, rW3 + t * 16384,
            A, nquad);
        node_update<<<NN, 256, 0, stream>>>(
            A, attrs, Wmix + t * 16384, Wz, Wout + t * 4096,
            wread1, Wr1, wr2, batch, feats, out, t);
    }
}

// Round 2
// 714.373 us; speedup vs baseline: 24.0011x; 24.0011x over previous
//
#include <hip/hip_runtime.h>
#include <hip/hip_bf16.h>
#include <math.h>

#define NN 10000
#define NE 160000
#define NZ 10
#define INV_AVG 0.0625f

__device__ __forceinline__ float silu(float x) { return x / (1.0f + expf(-x)); }

// ---------------------------------------------------------------------------
// feats0 = node_attrs @ W_embed ; out[batch[n]] += node_attrs @ atomic_energies
// ---------------------------------------------------------------------------
__global__ __launch_bounds__(256) void node_init(
    const float* __restrict__ attrs, const float* __restrict__ W_embed,
    const float* __restrict__ ae, const int* __restrict__ batch,
    float* __restrict__ feats, float* __restrict__ out)
{
    int gid = blockIdx.x * blockDim.x + threadIdx.x;
    if (gid >= NN * 64) return;
    int n = gid >> 6, k = gid & 63;
    float acc = 0.f;
#pragma unroll
    for (int z = 0; z < NZ; ++z) acc += attrs[n * NZ + z] * W_embed[z * 64 + k];
    feats[gid] = acc;
    if (k == 0) {
        float e0 = 0.f;
#pragma unroll
        for (int z = 0; z < NZ; ++z) e0 += attrs[n * NZ + z] * ae[z];
        atomicAdd(out + batch[n], e0);
    }
}

// ---------------------------------------------------------------------------
// CSR build: count / scan / scatter
// ---------------------------------------------------------------------------
__global__ __launch_bounds__(256) void csr_count(const int* __restrict__ ei, int* __restrict__ cnt)
{
    int e = blockIdx.x * 256 + threadIdx.x;
    if (e < NE) atomicAdd(&cnt[ei[NE + e]], 1);
}

__global__ __launch_bounds__(1024) void csr_scan(const int* __restrict__ cnt, int* __restrict__ row)
{
    __shared__ int part[1024];
    const int tid = threadIdx.x;
    const int base = tid * 10;
    int loc[10];
    int s = 0;
#pragma unroll
    for (int q = 0; q < 10; ++q) {
        int idx = base + q;
        int v = (idx < NN) ? cnt[idx] : 0;
        loc[q] = s; s += v;
    }
    part[tid] = s;
    __syncthreads();
    for (int off = 1; off < 1024; off <<= 1) {
        int v = (tid >= off) ? part[tid - off] : 0;
        __syncthreads();
        part[tid] += v;
        __syncthreads();
    }
    int pre = (tid > 0) ? part[tid - 1] : 0;
#pragma unroll
    for (int q = 0; q < 10; ++q) {
        int idx = base + q;
        if (idx < NN) row[idx] = pre + loc[q];
    }
    if (tid == 1023) row[NN] = part[1023];
}

__global__ __launch_bounds__(256) void csr_scatter(
    const int* __restrict__ ei, const int* __restrict__ row,
    int* __restrict__ cur, int* __restrict__ perm)
{
    int e = blockIdx.x * 256 + threadIdx.x;
    if (e < NE) {
        int r = ei[NE + e];
        int p = atomicAdd(&cur[r], 1);
        perm[row[r] + p] = e;
    }
}

// ---------------------------------------------------------------------------
// edge_mlp: geometry + Y + radial layers 1-3. One wave per 64 edges,
// lane-owns-edge; activations transposed through LDS sH[i][lane] so the
// runtime i index never hits scratch; weight indices are wave-uniform ->
// scalar loads.
// ---------------------------------------------------------------------------
__global__ __launch_bounds__(64) void edge_mlp(
    const int* __restrict__ ei, const float* __restrict__ pos,
    const float* __restrict__ W0, const float* __restrict__ W1, const float* __restrict__ W2,
    float* __restrict__ h3g, float* __restrict__ Yg)
{
    __shared__ float sH[64 * 64];
    const int lane = threadIdx.x;
    const int e = blockIdx.x * 64 + lane;

    const int snd = ei[e], rcv = ei[NE + e];
    const float dx = pos[rcv * 3 + 0] - pos[snd * 3 + 0];
    const float dy = pos[rcv * 3 + 1] - pos[snd * 3 + 1];
    const float dz = pos[rcv * 3 + 2] - pos[snd * 3 + 2];
    const float r = sqrtf(dx * dx + dy * dy + dz * dz + 1e-12f);
    const float ir = 1.0f / r;
    const float x = dx * ir, y = dy * ir, z = dz * ir;
    const float xx = x * x, yy = y * y, zz = z * z;

    {
        float4 y0, y1, y2, y3;
        y0.x = 1.0f;
        y0.y = 1.73205081f * x;
        y0.z = 1.73205081f * y;
        y0.w = 1.73205081f * z;
        y1.x = 3.87298335f * x * y;
        y1.y = 3.87298335f * y * z;
        y1.z = 1.11803399f * (3.0f * zz - 1.0f);
        y1.w = 3.87298335f * x * z;
        y2.x = 1.93649167f * (xx - yy);
        y2.y = 2.09165007f * y * (3.0f * xx - yy);
        y2.z = 10.2469508f * x * y * z;
        y2.w = 1.62018517f * y * (5.0f * zz - 1.0f);
        y3.x = 1.32287566f * z * (5.0f * zz - 3.0f);
        y3.y = 1.62018517f * x * (5.0f * zz - 1.0f);
        y3.z = 5.12347538f * z * (xx - yy);
        y3.w = 2.09165007f * x * (xx - 3.0f * yy);
        float4* Yp = (float4*)(Yg + (size_t)e * 16);
        Yp[0] = y0; Yp[1] = y1; Yp[2] = y2; Yp[3] = y3;
    }

    const float u = r * 0.2f;
    float env = 0.0f;
    if (u < 1.0f) {
        const float u2 = u * u, u5 = u2 * u2 * u;
        env = 1.0f - 21.0f * u5 + 35.0f * u5 * u - 15.0f * u5 * u2;
    }
    const float cb = 0.632455532f * ir * env;
    const float pu = 3.14159265358979f * u;
    float eb[8];
#pragma unroll
    for (int i = 0; i < 8; ++i) eb[i] = cb * sinf((float)(i + 1) * pu);

    // layer 1: 8 -> 64, results to sH[c][lane]
#pragma unroll
    for (int s = 0; s < 4; ++s) {
        float acc[16];
#pragma unroll
        for (int c = 0; c < 16; ++c) acc[c] = 0.f;
#pragma unroll
        for (int i = 0; i < 8; ++i) {
#pragma unroll
            for (int c = 0; c < 16; ++c) acc[c] += eb[i] * W0[i * 64 + s * 16 + c];
        }
#pragma unroll
        for (int c = 0; c < 16; ++c) sH[(s * 16 + c) * 64 + lane] = silu(acc[c]);
    }

    // layer 2: 64 -> 64, stash h2 in registers
    float h2[64];
#pragma unroll
    for (int s = 0; s < 4; ++s) {
        float acc[16];
#pragma unroll
        for (int c = 0; c < 16; ++c) acc[c] = 0.f;
#pragma unroll 4
        for (int i = 0; i < 64; ++i) {
            const float hv = sH[i * 64 + lane];
#pragma unroll
            for (int c = 0; c < 16; ++c) acc[c] += hv * W1[i * 64 + s * 16 + c];
        }
#pragma unroll
        for (int c = 0; c < 16; ++c) h2[s * 16 + c] = silu(acc[c]);
    }
#pragma unroll
    for (int i = 0; i < 64; ++i) sH[i * 64 + lane] = h2[i];

    // layer 3: 64 -> 64 -> global h3
#pragma unroll
    for (int s = 0; s < 4; ++s) {
        float acc[16];
#pragma unroll
        for (int c = 0; c < 16; ++c) acc[c] = 0.f;
#pragma unroll 4
        for (int i = 0; i < 64; ++i) {
            const float hv = sH[i * 64 + lane];
#pragma unroll
            for (int c = 0; c < 16; ++c) acc[c] += hv * W2[i * 64 + s * 16 + c];
        }
        float4* hp = (float4*)(h3g + (size_t)e * 64 + s * 16);
        hp[0] = make_float4(silu(acc[0]), silu(acc[1]), silu(acc[2]), silu(acc[3]));
        hp[1] = make_float4(silu(acc[4]), silu(acc[5]), silu(acc[6]), silu(acc[7]));
        hp[2] = make_float4(silu(acc[8]), silu(acc[9]), silu(acc[10]), silu(acc[11]));
        hp[3] = make_float4(silu(acc[12]), silu(acc[13]), silu(acc[14]), silu(acc[15]));
    }
}

// ---------------------------------------------------------------------------
// gather_update: wave per node. Layer-4 on the fly (W3 coalesced vector
// loads, h3 scalar loads), message accumulate (lane=k), then einsum + gate +
// W_out + energy, all in-wave. No atomics on A.
// ---------------------------------------------------------------------------
__global__ __launch_bounds__(256) void gather_update(
    const float* __restrict__ h3g, const float* __restrict__ Yg,
    const int* __restrict__ perm, const int* __restrict__ row,
    const int* __restrict__ ei, const float* __restrict__ feats_in,
    const float* __restrict__ attrs,
    const float* __restrict__ W3, const float* __restrict__ Wmix,
    const float* __restrict__ Wz, const float* __restrict__ Wout,
    const float* __restrict__ wread1, const float* __restrict__ Wr1,
    const float* __restrict__ wr2, const int* __restrict__ batch,
    float* __restrict__ feats_out, float* __restrict__ out, int t)
{
    __shared__ float sA[4][1024];
    __shared__ float sF[4][64];
    const int w = threadIdx.x >> 6;
    const int lane = threadIdx.x & 63;
    const int n = __builtin_amdgcn_readfirstlane(blockIdx.x * 4 + w);
    const int beg = row[n], end = row[n + 1];

    float acc[16];
#pragma unroll
    for (int m = 0; m < 16; ++m) acc[m] = 0.f;

    for (int g = beg; g < end; g += 8) {
        int rem = end - g; if (rem > 8) rem = 8;
        int ej[8], sj[8];
#pragma unroll
        for (int j = 0; j < 8; ++j) {
            ej[j] = perm[g + (j < rem ? j : 0)];
            sj[j] = ei[ej[j]];
        }
        float rw[8][4];
#pragma unroll
        for (int j = 0; j < 8; ++j) {
#pragma unroll
            for (int l = 0; l < 4; ++l) rw[j][l] = 0.f;
        }
#pragma unroll 4
        for (int i = 0; i < 64; ++i) {
            const float4 wv = *(const float4*)(W3 + i * 256 + lane * 4);
#pragma unroll
            for (int j = 0; j < 8; ++j) {
                const float hj = h3g[(size_t)ej[j] * 64 + i];
                rw[j][0] += hj * wv.x; rw[j][1] += hj * wv.y;
                rw[j][2] += hj * wv.z; rw[j][3] += hj * wv.w;
            }
        }
#pragma unroll
        for (int j = 0; j < 8; ++j) {
            if (j < rem) {
                const float f = feats_in[(size_t)sj[j] * 64 + lane];
                const float p0 = f * rw[j][0], p1 = f * rw[j][1];
                const float p2 = f * rw[j][2], p3 = f * rw[j][3];
                const float* Ye = Yg + (size_t)ej[j] * 16;
                acc[0]  += p0 * Ye[0];
                acc[1]  += p1 * Ye[1];  acc[2]  += p1 * Ye[2];  acc[3]  += p1 * Ye[3];
                acc[4]  += p2 * Ye[4];  acc[5]  += p2 * Ye[5];  acc[6]  += p2 * Ye[6];
                acc[7]  += p2 * Ye[7];  acc[8]  += p2 * Ye[8];
                acc[9]  += p3 * Ye[9];  acc[10] += p3 * Ye[10]; acc[11] += p3 * Ye[11];
                acc[12] += p3 * Ye[12]; acc[13] += p3 * Ye[13]; acc[14] += p3 * Ye[14];
                acc[15] += p3 * Ye[15];
            }
        }
    }
#pragma unroll
    for (int m = 0; m < 16; ++m) acc[m] *= INV_AVG;

    // A (lane=k) -> LDS [k][m]
    float4* sAv = (float4*)&sA[w][lane * 16];
    sAv[0] = make_float4(acc[0], acc[1], acc[2], acc[3]);
    sAv[1] = make_float4(acc[4], acc[5], acc[6], acc[7]);
    sAv[2] = make_float4(acc[8], acc[9], acc[10], acc[11]);
    sAv[3] = make_float4(acc[12], acc[13], acc[14], acc[15]);

    // einsum: new[m][c] = sum_k A[k][m] * Wmix[l(m)][k][c], lane = c
    float accq[16];
#pragma unroll
    for (int m = 0; m < 16; ++m) accq[m] = 0.f;
    for (int k = 0; k < 64; ++k) {
        const float4 a0 = *(const float4*)&sA[w][k * 16 + 0];
        const float4 a1 = *(const float4*)&sA[w][k * 16 + 4];
        const float4 a2 = *(const float4*)&sA[w][k * 16 + 8];
        const float4 a3 = *(const float4*)&sA[w][k * 16 + 12];
        const float wl0 = Wmix[0 * 4096 + k * 64 + lane];
        const float wl1 = Wmix[1 * 4096 + k * 64 + lane];
        const float wl2 = Wmix[2 * 4096 + k * 64 + lane];
        const float wl3 = Wmix[3 * 4096 + k * 64 + lane];
        accq[0]  += a0.x * wl0;
        accq[1]  += a0.y * wl1; accq[2]  += a0.z * wl1; accq[3]  += a0.w * wl1;
        accq[4]  += a1.x * wl2; accq[5]  += a1.y * wl2; accq[6]  += a1.z * wl2;
        accq[7]  += a1.w * wl2; accq[8]  += a2.x * wl2;
        accq[9]  += a2.y * wl3; accq[10] += a2.z * wl3; accq[11] += a2.w * wl3;
        accq[12] += a3.x * wl3; accq[13] += a3.y * wl3; accq[14] += a3.z * wl3;
        accq[15] += a3.w * wl3;
    }

    const float s1 = accq[0];
    float inv2 = 0.f;
#pragma unroll
    for (int m = 0; m < 16; ++m) inv2 += accq[m] * accq[m];

    float z0 = 0.f, z1 = 0.f, z2 = 0.f;
#pragma unroll
    for (int zz = 0; zz < NZ; ++zz) {
        const float a = attrs[n * NZ + zz];
        z0 += a * Wz[(t * 3 + 0) * 640 + zz * 64 + lane];
        z1 += a * Wz[(t * 3 + 1) * 640 + zz * 64 + lane];
        z2 += a * Wz[(t * 3 + 2) * 640 + zz * 64 + lane];
    }
    const float b = z0 * s1 + z1 * inv2 + z2 * (s1 * inv2);

    sF[w][lane] = b;
    float fnew = 0.f;
#pragma unroll 8
    for (int j = 0; j < 64; ++j) fnew += sF[w][j] * Wout[j * 64 + lane];
    feats_out[(size_t)n * 64 + lane] = fnew;

    if (t == 0) {
        float v = fnew * wread1[lane];
#pragma unroll
        for (int off = 32; off > 0; off >>= 1) v += __shfl_down(v, off, 64);
        if (lane == 0) atomicAdd(out + batch[n], v);
    } else {
        sF[w][lane] = fnew;
        if (lane < 16) {
            float a = 0.f;
#pragma unroll 8
            for (int j = 0; j < 64; ++j) a += sF[w][j] * Wr1[j * 16 + lane];
            float vv = silu(a) * wr2[lane];
            vv += __shfl_down(vv, 8, 64);
            vv += __shfl_down(vv, 4, 64);
            vv += __shfl_down(vv, 2, 64);
            vv += __shfl_down(vv, 1, 64);
            if (lane == 0) atomicAdd(out + batch[n], vv);
        }
    }
}

// ---------------------------------------------------------------------------
extern "C" void kernel_launch(void* const* d_in, const int* in_sizes, int n_in,
                              void* d_out, int out_size, void* d_ws, size_t ws_size,
                              hipStream_t stream) {
    const float* attrs   = (const float*)d_in[0];
    const float* pos     = (const float*)d_in[1];
    const int*   ei      = (const int*)d_in[2];
    const int*   batch   = (const int*)d_in[3];
    const float* ae      = (const float*)d_in[4];
    const float* W_embed = (const float*)d_in[5];
    const float* rW0     = (const float*)d_in[6];
    const float* rW1     = (const float*)d_in[7];
    const float* rW2     = (const float*)d_in[8];
    const float* rW3     = (const float*)d_in[9];
    const float* Wmix    = (const float*)d_in[10];
    const float* Wz      = (const float*)d_in[11];
    const float* Wout    = (const float*)d_in[12];
    const float* wread1  = (const float*)d_in[13];
    const float* Wr1     = (const float*)d_in[14];
    const float* wr2     = (const float*)d_in[15];
    float* out = (float*)d_out;

    char* ws = (char*)d_ws;
    float* h3g    = (float*)(ws);                    // 160000*64*4  = 40,960,000
    float* Yg     = (float*)(ws + 40960000);         // 160000*16*4  = 10,240,000
    float* feats0 = (float*)(ws + 51200000);         // 10000*64*4   =  2,560,000
    float* feats1 = (float*)(ws + 53760000);         //              =  2,560,000
    int*   cnt    = (int*)  (ws + 56320000);         // 10000*4
    int*   cur    = (int*)  (ws + 56360000);         // 10000*4
    int*   rowst  = (int*)  (ws + 56400000);         // 10001*4 (padded)
    int*   perm   = (int*)  (ws + 56440016);         // 160000*4

    hipMemsetAsync(out, 0, out_size * sizeof(float), stream);
    hipMemsetAsync(cnt, 0, 80000, stream);           // cnt + cur contiguous

    node_init<<<2500, 256, 0, stream>>>(attrs, W_embed, ae, batch, feats0, out);

    csr_count<<<625, 256, 0, stream>>>(ei, cnt);
    csr_scan<<<1, 1024, 0, stream>>>(cnt, rowst);
    csr_scatter<<<625, 256, 0, stream>>>(ei, rowst, cur, perm);

    for (int t = 0; t < 2; ++t) {
        edge_mlp<<<2500, 64, 0, stream>>>(
            ei, pos, rW0 + t * 512, rW1 + t * 4096, rW2 + t * 4096, h3g, Yg);
        gather_update<<<2500, 256, 0, stream>>>(
            h3g, Yg, perm, rowst, ei,
            (t == 0) ? feats0 : feats1, attrs,
            rW3 + t * 16384, Wmix + t * 16384, Wz,
            Wout + t * 4096, wread1, Wr1, wr2, batch,
            (t == 0) ? feats1 : feats0, out, t);
    }
}